// Round 10
// baseline (170.401 us; speedup 1.0000x reference)
//
#include <hip/hip_runtime.h>
#include <stdint.h>

// Toeplitz matvec = circular conv via batched 4096-pt radix-16 FFT (3 stages).
// v20: two register/bank micro-fixes on the converged v19 structure.
// (1) prep transpose tile pad 66 -> 65: the tile WRITE pattern (stride
//     4*ROW dwords per lane) had 4-way bank conflicts at ROW=66 (264%32=8 ->
//     banks {0,8,16,24} x4 lanes); ROW=65 gives 260%32=4 and the per-quarter
//     j-offset spreads all 32 banks at exactly 2 lanes = free.
// (2) fft_conv: rematerialize phase-base values (bAE/bBD/bC) inside each
//     phase instead of hoisting them live across the whole kernel. v19's
//     natural VGPR was 104; the 5-blocks/CU threshold is 102 (512/5 waves per
//     SIMD). No cap is applied (v14/16/18: any cap below natural collapses);
//     if the allocator lands <=102 naturally, LDS (32KB -> 5 blocks) gives
//     20 waves/CU instead of 16. If it stays 104, this is a no-op.
// Falsified levers (do not retry): occupancy via threads/LDS (v13-17),
// 8B strided stores (v13), VGPR caps (v14/16/18), XOR-affine addr (v19 -- kept
// since it's free, but it bought ~0: kernel is latency-bound, not issue-bound).
// ws: xP u32[8][512][2048] (32MiB) + tw4096 f2[4096] + tw256 f2[256] + V2 f2[4096].

#define B_ 8
#define N_ 2048
#define NF 4096
#define E_ 1024

// Bank swizzle, b32 banks (bank = idx mod 32). All phase patterns
// (t+256r / 256g+16r+j / 16t+r) verified exactly 2 lanes/bank = free (m136).
__device__ __forceinline__ int P(int n) {
    return n ^ ((n >> 4) & 15) ^ ((n >> 8) & 15) ^ (((n >> 9) & 1) << 4);
}
#define PERM(r) ((((r) & 3) << 2) | ((r) >> 2))   // DFT16 reg<->index transpose

// XOR-affine byte-offset keys (compile-time for unrolled constant r):
//  A/E pattern n = t + 256r : P = (t ^ (t>>4)) ^ [(r<<8) ^ r ^ (((r>>1)&1)<<4)]
//  B/D pattern n = 256g+16r+j: P = ((g<<8)^j^g^(((g>>1)&1)<<4)) ^ [(r<<4)^r]
//  C   pattern n = 16t + r  : P = ((t<<4)^(t&15)^((t>>4)&15)^(((t>>5)&1)<<4)) ^ r
#define KAE(r) (((((r) << 8) ^ (r)) ^ ((((r) >> 1) & 1) << 4)) << 2)
#define KBD(r) (((((r) << 4) ^ (r))) << 2)

__device__ __forceinline__ uint32_t ldsr(const uint32_t* b, int off) {
    return *(const uint32_t*)((const char*)b + off);
}
__device__ __forceinline__ void ldsw(uint32_t* b, int off, uint32_t v) {
    *(uint32_t*)((char*)b + off) = v;
}

// pack complex (re,im) -> u32: low16 = bf16(re), high16 = bf16(im).
// HW packed convert, RNE (gfx950).
__device__ __forceinline__ uint32_t cpack(float re, float im) {
    uint32_t r;
    asm("v_cvt_pk_bf16_f32 %0, %1, %2" : "=v"(r) : "v"(re), "v"(im));
    return r;
}
__device__ __forceinline__ void cunpack(uint32_t u, float& re, float& im) {
    union { uint32_t u; float f; } a, b;
    a.u = u << 16; b.u = u & 0xffff0000u;
    re = a.f; im = b.f;
}
__device__ __forceinline__ void cmul(float& ar, float& ai, float br, float bi) {
    float t = ar * br - ai * bi; ai = ar * bi + ai * br; ar = t;
}
__device__ __forceinline__ void cmulc(float& ar, float& ai, float br, float bi) {
    float t = ar * br + ai * bi; ai = ai * br - ar * bi; ar = t;   // a *= conj(b)
}

__device__ __forceinline__ void dft4(float& x0r, float& x0i, float& x1r, float& x1i,
                                     float& x2r, float& x2i, float& x3r, float& x3i,
                                     float sg) {
    float t0r = x0r + x2r, t0i = x0i + x2i;
    float t1r = x0r - x2r, t1i = x0i - x2i;
    float t2r = x1r + x3r, t2i = x1i + x3i;
    float t3r = x1r - x3r, t3i = x1i - x3i;
    x0r = t0r + t2r; x0i = t0i + t2i;
    x2r = t0r - t2r; x2i = t0i - t2i;
    x1r = t1r - sg * t3i; x1i = t1i + sg * t3r;
    x3r = t1r + sg * t3i; x3i = t1i - sg * t3r;
}

template<int SG>
__device__ __forceinline__ void dft16_layer1(float* xr, float* xi) {
    const float sg = (float)SG;
#pragma unroll
    for (int n0 = 0; n0 < 4; ++n0)
        dft4(xr[n0], xi[n0], xr[n0 + 4], xi[n0 + 4],
             xr[n0 + 8], xi[n0 + 8], xr[n0 + 12], xi[n0 + 12], sg);
}
// upper 8 inputs (slots 8..15) known zero
template<int SG>
__device__ __forceinline__ void dft16_layer1_pad(float* xr, float* xi) {
    const float sg = (float)SG;
#pragma unroll
    for (int n0 = 0; n0 < 4; ++n0) {
        float ar = xr[n0], ai = xi[n0], br = xr[n0 + 4], bi = xi[n0 + 4];
        xr[n0]      = ar + br;       xi[n0]      = ai + bi;
        xr[n0 + 4]  = ar - sg * bi;  xi[n0 + 4]  = ai + sg * br;
        xr[n0 + 8]  = ar - br;       xi[n0 + 8]  = ai - bi;
        xr[n0 + 12] = ar + sg * bi;  xi[n0 + 12] = ai - sg * br;
    }
}
template<int SG>
__device__ __forceinline__ void dft16_twiddle(float* xr, float* xi) {
    const float sg = (float)SG;
    const float C1 = 0.923879532511286756f;
    const float S1 = 0.382683432365089772f;
    const float H  = 0.707106781186547524f;
    cmul(xr[5],  xi[5],  C1,  sg * S1);
    cmul(xr[9],  xi[9],  H,   sg * H);
    cmul(xr[13], xi[13], S1,  sg * C1);
    cmul(xr[6],  xi[6],  H,   sg * H);
    cmul(xr[10], xi[10], 0.f, sg);
    cmul(xr[14], xi[14], -H,  sg * H);
    cmul(xr[7],  xi[7],  S1,  sg * C1);
    cmul(xr[11], xi[11], -H,  sg * H);
    cmul(xr[15], xi[15], -C1, -sg * S1);
}
template<int SG>
__device__ __forceinline__ void dft16_layer2(float* xr, float* xi) {
    const float sg = (float)SG;
#pragma unroll
    for (int k1 = 0; k1 < 4; ++k1)
        dft4(xr[4 * k1], xi[4 * k1], xr[4 * k1 + 1], xi[4 * k1 + 1],
             xr[4 * k1 + 2], xi[4 * k1 + 2], xr[4 * k1 + 3], xi[4 * k1 + 3], sg);
}
template<int SG>
__device__ __forceinline__ void dft16(float* xr, float* xi) {
    dft16_layer1<SG>(xr, xi);
    dft16_twiddle<SG>(xr, xi);
    dft16_layer2<SG>(xr, xi);
}

// forward radix-16 stage with inline sincos twiddles (V build only, 1 block)
template<int L>
__device__ __forceinline__ void fwd_stage_sincos(float2* buf, int t) {
    constexpr int Lq = L / 16;
    int g = t / Lq;
    int j = t - g * Lq;
    int base = g * L + j;
    const float TPI = -6.28318530717958647692f;
    float xr[16], xi[16];
#pragma unroll
    for (int r = 0; r < 16; ++r) {
        float2 v = buf[P(base + r * Lq)];
        xr[r] = v.x; xi[r] = v.y;
    }
    dft16<-1>(xr, xi);
    { float2 v; v.x = xr[0]; v.y = xi[0]; buf[P(base)] = v; }
#pragma unroll
    for (int r = 1; r < 16; ++r) {
        float s, c;
        __sincosf(TPI * (float)(j * r) * (1.f / (float)L), &s, &c);
        float yr = xr[PERM(r)], yi = xi[PERM(r)];
        cmul(yr, yi, c, s);
        float2 v; v.x = yr; v.y = yi;
        buf[P(base + r * Lq)] = v;
    }
}

// ---------------- prep: tables + V + pair-interleaved transpose --------------
__global__ __launch_bounds__(256) void prep(const float* __restrict__ x,
                                            const float* __restrict__ pos,
                                            const float* __restrict__ zero,
                                            const float* __restrict__ neg,
                                            uint32_t* __restrict__ xP,
                                            float2* __restrict__ tw4096,
                                            float2* __restrict__ tw256,
                                            float2* __restrict__ V2) {
    __shared__ __align__(16) char smraw[32768];
    const float TPI = -6.28318530717958647692f;
    int blk = blockIdx.x, t = threadIdx.x;
    if (blk < 16) {
        float s, c;
        __sincosf(TPI * (float)(blk * t) * (1.f / 4096.f), &s, &c);
        float2 v; v.x = c; v.y = s;
        tw4096[blk * 256 + t] = v;
    } else if (blk == 16) {
        int r = t >> 4, j = t & 15;
        float s, c;
        __sincosf(TPI * (float)(r * j) * (1.f / 256.f), &s, &c);
        float2 v; v.x = c; v.y = s;
        tw256[t] = v;
    } else if (blk == 17) {
        float2* buf = (float2*)smraw;
#pragma unroll
        for (int it = 0; it < 16; ++it) {
            int n = t + 256 * it;
            float v;
            if (n == 0) v = zero[0];
            else if (n < N_) v = pos[n - 1];
            else if (n == N_) v = zero[0];
            else v = neg[n - (N_ + 1)];
            float2 cc; cc.x = v; cc.y = 0.f;
            buf[P(n)] = cc;
        }
        __syncthreads();
        fwd_stage_sincos<4096>(buf, t); __syncthreads();
        fwd_stage_sincos<256>(buf, t);  __syncthreads();
        fwd_stage_sincos<16>(buf, t);   __syncthreads();
        const float s = 1.f / (float)NF;
#pragma unroll
        for (int it = 0; it < 16; ++it) {
            int n = t + 256 * it;
            float2 c = buf[P(n)];
            c.x *= s; c.y *= s;
            V2[n] = c;
        }
    } else {
        float (*tile)[65] = (float (*)[65])smraw;    // 64*65*4 = 16.6 KB (pad 65: 2-way banks)
        int tid = blk - 18;
        int e0 = (tid & 15) * 64;                    // e-tile base
        int j0 = ((tid >> 4) & 31) * 64;             // n-tile base
        int b  = tid >> 9;
        int e4 = t & 15, jr = t >> 4;
#pragma unroll
        for (int it = 0; it < 4; ++it) {
            int j = jr + it * 16;
            const float4 v = *(const float4*)(x + ((size_t)(b * N_ + j0 + j) * E_) + e0 + e4 * 4);
            tile[e4 * 4 + 0][j] = v.x;
            tile[e4 * 4 + 1][j] = v.y;
            tile[e4 * 4 + 2][j] = v.z;
            tile[e4 * 4 + 3][j] = v.w;
        }
        __syncthreads();
        int jj = t & 63, ur = t >> 6;                // ur 0..3
#pragma unroll
        for (int it = 0; it < 8; ++it) {
            int u = ur + it * 4;                     // pair-local 0..31
            uint32_t w = cpack(tile[2 * u][jj], tile[2 * u + 1][jj]);
            xP[((size_t)(b * 512 + (e0 >> 1) + u)) * N_ + j0 + jj] = w;
        }
    }
}

// ---------------- main: FFT-conv, TWO pairs/block, bf16-packed LDS -----------
// v19 structure; phase bases rematerialized per-phase (no long-lived regs).
__global__ __launch_bounds__(256) void fft_conv(const uint32_t* __restrict__ xP,
                                                const float2* __restrict__ tw4096,
                                                const float2* __restrict__ tw256,
                                                const float2* __restrict__ V2,
                                                float* __restrict__ out) {
    __shared__ uint32_t buf0[NF];           // 16 KB
    __shared__ uint32_t buf1[NF];           // 16 KB -> 32 KB total
    int t = threadIdx.x;
    int bid = blockIdx.x;                   // 2048
    int xcd = bid & 7;
    int q = bid >> 3;                       // 0..255
    int b = q >> 5;                         // 0..7
    int quad = xcd * 32 + (q & 31);         // 0..255 -> e0 = quad*4
    const uint32_t* g0 = xP + ((size_t)(b * 512 + quad * 2)) * N_;
    const uint32_t* g1 = g0 + N_;

    float x0r[16], x0i[16], x1r[16], x1i[16];

    // ---- Phase A: fwd L=4096 from global; slots 8..15 zero
#pragma unroll
    for (int r = 0; r < 8; ++r) {
        int n = t + 256 * r;
        cunpack(g0[n], x0r[r], x0i[r]);
        cunpack(g1[n], x1r[r], x1i[r]);
    }
#pragma unroll
    for (int r = 8; r < 16; ++r) { x0r[r] = 0.f; x0i[r] = 0.f; x1r[r] = 0.f; x1i[r] = 0.f; }
    dft16_layer1_pad<-1>(x0r, x0i); dft16_layer1_pad<-1>(x1r, x1i);
    dft16_twiddle<-1>(x0r, x0i);    dft16_twiddle<-1>(x1r, x1i);
    dft16_layer2<-1>(x0r, x0i);     dft16_layer2<-1>(x1r, x1i);
    {
        const int bAE = (t ^ (t >> 4)) << 2;        // rematerialized
        ldsw(buf0, bAE, cpack(x0r[0], x0i[0]));
        ldsw(buf1, bAE, cpack(x1r[0], x1i[0]));
#pragma unroll
        for (int r = 1; r < 16; ++r) {
            float2 w = tw4096[r * 256 + t];             // shared twiddle
            int a = bAE ^ KAE(r);
            float y0r = x0r[PERM(r)], y0i = x0i[PERM(r)];
            cmul(y0r, y0i, w.x, w.y);
            ldsw(buf0, a, cpack(y0r, y0i));
            float y1r = x1r[PERM(r)], y1i = x1i[PERM(r)];
            cmul(y1r, y1i, w.x, w.y);
            ldsw(buf1, a, cpack(y1r, y1i));
        }
    }
    __syncthreads();

    // ---- Phase B: fwd L=256
    {
        const int gg = t >> 4, j = t & 15;          // rematerialized
        const int bBD = ((gg << 8) ^ j ^ gg ^ (((gg >> 1) & 1) << 4)) << 2;
#pragma unroll
        for (int r = 0; r < 16; ++r) {
            int a = bBD ^ KBD(r);
            cunpack(ldsr(buf0, a), x0r[r], x0i[r]);
            cunpack(ldsr(buf1, a), x1r[r], x1i[r]);
        }
        dft16<-1>(x0r, x0i); dft16<-1>(x1r, x1i);
        ldsw(buf0, bBD, cpack(x0r[0], x0i[0]));
        ldsw(buf1, bBD, cpack(x1r[0], x1i[0]));
#pragma unroll
        for (int r = 1; r < 16; ++r) {
            float2 w = tw256[r * 16 + j];
            int a = bBD ^ KBD(r);
            float y0r = x0r[PERM(r)], y0i = x0i[PERM(r)];
            cmul(y0r, y0i, w.x, w.y);
            ldsw(buf0, a, cpack(y0r, y0i));
            float y1r = x1r[PERM(r)], y1i = x1i[PERM(r)];
            cmul(y1r, y1i, w.x, w.y);
            ldsw(buf1, a, cpack(y1r, y1i));
        }
    }
    __syncthreads();

    // ---- Phase C: fwd L=16 + pointwise*V (shared) + inv L=16, in place
    {
        const int bC = ((t << 4) ^ (t & 15) ^ ((t >> 4) & 15) ^ (((t >> 5) & 1) << 4)) << 2;
        int mb = 16 * t;
#pragma unroll
        for (int r = 0; r < 16; ++r) {
            int a = bC ^ (r << 2);
            cunpack(ldsr(buf0, a), x0r[r], x0i[r]);
            cunpack(ldsr(buf1, a), x1r[r], x1i[r]);
        }
        dft16<-1>(x0r, x0i); dft16<-1>(x1r, x1i);
        // y[r] = x[PERM(r)]*V[r]; PERM involution -> pair swap, V shared
#pragma unroll
        for (int r = 0; r < 16; ++r) {
            int p = PERM(r);
            if (p < r) continue;
            if (p == r) {
                float2 vv = V2[mb + r];
                float ar = x0r[r], ai = x0i[r];
                x0r[r] = ar * vv.x - ai * vv.y; x0i[r] = ar * vv.y + ai * vv.x;
                ar = x1r[r]; ai = x1i[r];
                x1r[r] = ar * vv.x - ai * vv.y; x1i[r] = ar * vv.y + ai * vv.x;
            } else {
                float2 va = V2[mb + r], vb = V2[mb + p];
                float ar = x0r[r], ai = x0i[r], br = x0r[p], bi = x0i[p];
                x0r[r] = br * va.x - bi * va.y; x0i[r] = br * va.y + bi * va.x;
                x0r[p] = ar * vb.x - ai * vb.y; x0i[p] = ar * vb.y + ai * vb.x;
                ar = x1r[r]; ai = x1i[r]; br = x1r[p]; bi = x1i[p];
                x1r[r] = br * va.x - bi * va.y; x1i[r] = br * va.y + bi * va.x;
                x1r[p] = ar * vb.x - ai * vb.y; x1i[p] = ar * vb.y + ai * vb.x;
            }
        }
        dft16<1>(x0r, x0i); dft16<1>(x1r, x1i);
#pragma unroll
        for (int r = 0; r < 16; ++r) {
            int a = bC ^ (r << 2);
            ldsw(buf0, a, cpack(x0r[PERM(r)], x0i[PERM(r)]));
            ldsw(buf1, a, cpack(x1r[PERM(r)], x1i[PERM(r)]));
        }
    }
    __syncthreads();

    // ---- Phase D: inv L=256
    {
        const int gg = t >> 4, j = t & 15;          // rematerialized
        const int bBD = ((gg << 8) ^ j ^ gg ^ (((gg >> 1) & 1) << 4)) << 2;
#pragma unroll
        for (int r = 0; r < 16; ++r) {
            int a = bBD ^ KBD(r);
            cunpack(ldsr(buf0, a), x0r[r], x0i[r]);
            cunpack(ldsr(buf1, a), x1r[r], x1i[r]);
        }
#pragma unroll
        for (int r = 1; r < 16; ++r) {
            float2 w = tw256[r * 16 + j];
            cmulc(x0r[r], x0i[r], w.x, w.y);
            cmulc(x1r[r], x1i[r], w.x, w.y);
        }
        dft16<1>(x0r, x0i); dft16<1>(x1r, x1i);
#pragma unroll
        for (int r = 0; r < 16; ++r) {
            int a = bBD ^ KBD(r);
            ldsw(buf0, a, cpack(x0r[PERM(r)], x0i[PERM(r)]));
            ldsw(buf1, a, cpack(x1r[PERM(r)], x1i[PERM(r)]));
        }
    }
    __syncthreads();

    // ---- Phase E: inv L=4096, pruned (k<2048), fused float4 stores (4 cols)
    {
        const int bAE = (t ^ (t >> 4)) << 2;        // rematerialized
#pragma unroll
        for (int r = 0; r < 16; ++r) {
            int a = bAE ^ KAE(r);
            cunpack(ldsr(buf0, a), x0r[r], x0i[r]);
            cunpack(ldsr(buf1, a), x1r[r], x1i[r]);
        }
    }
#pragma unroll
    for (int r = 1; r < 16; ++r) {
        float2 w = tw4096[r * 256 + t];
        cmulc(x0r[r], x0i[r], w.x, w.y);
        cmulc(x1r[r], x1i[r], w.x, w.y);
    }
    dft16_layer1<1>(x0r, x0i); dft16_layer1<1>(x1r, x1i);
    dft16_twiddle<1>(x0r, x0i); dft16_twiddle<1>(x1r, x1i);
    float* ob = out + ((size_t)b * N_) * E_ + quad * 4;
#pragma unroll
    for (int k1 = 0; k1 < 4; ++k1) {
        // pruned final dft4 (outputs r=k1 and r=k1+4 only), both streams
        float a0r = x0r[4 * k1],     a0i = x0i[4 * k1];
        float a1r = x0r[4 * k1 + 1], a1i = x0i[4 * k1 + 1];
        float a2r = x0r[4 * k1 + 2], a2i = x0i[4 * k1 + 2];
        float a3r = x0r[4 * k1 + 3], a3i = x0i[4 * k1 + 3];
        float t0r = a0r + a2r, t0i = a0i + a2i;
        float t1r = a0r - a2r, t1i = a0i - a2i;
        float t2r = a1r + a3r, t2i = a1i + a3i;
        float t3r = a1r - a3r, t3i = a1i - a3i;
        float s0v0r = t0r + t2r, s0v0i = t0i + t2i;
        float s0v1r = t1r - t3i, s0v1i = t1i + t3r;
        a0r = x1r[4 * k1];     a0i = x1i[4 * k1];
        a1r = x1r[4 * k1 + 1]; a1i = x1i[4 * k1 + 1];
        a2r = x1r[4 * k1 + 2]; a2i = x1i[4 * k1 + 2];
        a3r = x1r[4 * k1 + 3]; a3i = x1i[4 * k1 + 3];
        t0r = a0r + a2r; t0i = a0i + a2i;
        t1r = a0r - a2r; t1i = a0i - a2i;
        t2r = a1r + a3r; t2i = a1i + a3i;
        t3r = a1r - a3r; t3i = a1i - a3i;
        float s1v0r = t0r + t2r, s1v0i = t0i + t2i;
        float s1v1r = t1r - t3i, s1v1i = t1i + t3r;
        float4 w0; w0.x = s0v0r; w0.y = s0v0i; w0.z = s1v0r; w0.w = s1v0i;
        float4 w1; w1.x = s0v1r; w1.y = s0v1i; w1.z = s1v1r; w1.w = s1v1i;
        *(float4*)(ob + (size_t)(t + 256 * k1) * E_)       = w0;   // k=t+256k1
        *(float4*)(ob + (size_t)(t + 256 * (k1 + 4)) * E_) = w1;   // k=t+256(k1+4)
    }
}

// ---------------- fallback (ws too small): direct fp32 dot -------------------
__global__ __launch_bounds__(256) void naive_toep(const float* __restrict__ x,
                                                  const float* __restrict__ pos,
                                                  const float* __restrict__ zero,
                                                  const float* __restrict__ neg,
                                                  float* __restrict__ out) {
    int bid = blockIdx.x;
    int e   = (bid & 3) * 256 + threadIdx.x;
    int k   = (bid >> 2) & (N_ - 1);
    int b   = bid >> 13;
    float zv = zero[0];
    float acc = 0.f;
    const float* xb = x + (size_t)b * N_ * E_ + e;
    for (int jj = 0; jj < N_; ++jj) {
        float c = (jj < k) ? pos[k - jj - 1] : (jj == k) ? zv : neg[N_ - 1 - jj + k];
        acc += c * xb[(size_t)jj * E_];
    }
    out[((size_t)(b * N_ + k)) * E_ + e] = acc;
}

extern "C" void kernel_launch(void* const* d_in, const int* in_sizes, int n_in,
                              void* d_out, int out_size, void* d_ws, size_t ws_size,
                              hipStream_t stream) {
    const float* x    = (const float*)d_in[0];
    const float* pos  = (const float*)d_in[1];
    const float* zero = (const float*)d_in[2];
    const float* neg  = (const float*)d_in[3];
    float* out = (float*)d_out;

    const size_t needX = (size_t)B_ * 512 * N_ * sizeof(uint32_t);   // 32 MiB
    const size_t need  = needX + (2 * (size_t)NF + 256) * sizeof(float2);
    if (ws_size >= need) {
        uint32_t* xP   = (uint32_t*)d_ws;
        float2* tw4096 = (float2*)((char*)d_ws + needX);
        float2* tw256  = tw4096 + NF;
        float2* V2     = tw256 + 256;
        prep<<<18 + 4096, 256, 0, stream>>>(x, pos, zero, neg, xP, tw4096, tw256, V2);
        fft_conv<<<2048, 256, 0, stream>>>(xP, tw4096, tw256, V2, out);
    } else {
        naive_toep<<<65536, 256, 0, stream>>>(x, pos, zero, neg, out);
    }
}

// Round 11
// 167.745 us; speedup vs baseline: 1.0158x; 1.0158x over previous
//
#include <hip/hip_runtime.h>
#include <stdint.h>

// Toeplitz matvec = circular conv via batched 4096-pt radix-16 FFT (3 stages).
// v21: remove the two provably-unneeded interior barriers. Phase dataflow:
//   A writes n=t+256r      -> one elem in EVERY 256-group -> cross-wave (keep barrier)
//   B r/w n=256g+16r+j, g=t>>4 -> only group t>>4
//   C r/w n=16t..16t+15        -> group 16t>>8 = t>>4
//   D r/w n=256g+16r+j, g=t>>4 -> only group t>>4
//   E reads t+256r             -> every group (keep barrier after D)
// Groups are 16-thread aligned and 16|64 -> each wave owns groups 4w..4w+3
// exclusively through B->C->D. The barriers after B and after C synchronize
// only wave-private data: REMOVED. Gains: 2 fewer full-block drains AND wave
// desync across B/C/D (one wave's dft16 chain overlaps another's LDS traffic
// -- the latency hiding lockstep was preventing; explains v13-17 nulls).
// Everything else = v20 (XOR-affine addr, cvt_pk packing, pad-65 prep).
// Falsified levers (do not retry): occupancy (v13-17), 8B stores (v13),
// VGPR caps (v14/16/18 -- collapse), issue-count cuts (v19 -- latency-bound).
// ws: xP u32[8][512][2048] (32MiB) + tw4096 f2[4096] + tw256 f2[256] + V2 f2[4096].

#define B_ 8
#define N_ 2048
#define NF 4096
#define E_ 1024

// Bank swizzle, b32 banks (bank = idx mod 32). All phase patterns
// (t+256r / 256g+16r+j / 16t+r) verified exactly 2 lanes/bank = free (m136).
__device__ __forceinline__ int P(int n) {
    return n ^ ((n >> 4) & 15) ^ ((n >> 8) & 15) ^ (((n >> 9) & 1) << 4);
}
#define PERM(r) ((((r) & 3) << 2) | ((r) >> 2))   // DFT16 reg<->index transpose

// XOR-affine byte-offset keys (compile-time for unrolled constant r):
//  A/E pattern n = t + 256r : P = (t ^ (t>>4)) ^ [(r<<8) ^ r ^ (((r>>1)&1)<<4)]
//  B/D pattern n = 256g+16r+j: P = ((g<<8)^j^g^(((g>>1)&1)<<4)) ^ [(r<<4)^r]
//  C   pattern n = 16t + r  : P = ((t<<4)^(t&15)^((t>>4)&15)^(((t>>5)&1)<<4)) ^ r
#define KAE(r) (((((r) << 8) ^ (r)) ^ ((((r) >> 1) & 1) << 4)) << 2)
#define KBD(r) (((((r) << 4) ^ (r))) << 2)

__device__ __forceinline__ uint32_t ldsr(const uint32_t* b, int off) {
    return *(const uint32_t*)((const char*)b + off);
}
__device__ __forceinline__ void ldsw(uint32_t* b, int off, uint32_t v) {
    *(uint32_t*)((char*)b + off) = v;
}

// pack complex (re,im) -> u32: low16 = bf16(re), high16 = bf16(im).
// HW packed convert, RNE (gfx950).
__device__ __forceinline__ uint32_t cpack(float re, float im) {
    uint32_t r;
    asm("v_cvt_pk_bf16_f32 %0, %1, %2" : "=v"(r) : "v"(re), "v"(im));
    return r;
}
__device__ __forceinline__ void cunpack(uint32_t u, float& re, float& im) {
    union { uint32_t u; float f; } a, b;
    a.u = u << 16; b.u = u & 0xffff0000u;
    re = a.f; im = b.f;
}
__device__ __forceinline__ void cmul(float& ar, float& ai, float br, float bi) {
    float t = ar * br - ai * bi; ai = ar * bi + ai * br; ar = t;
}
__device__ __forceinline__ void cmulc(float& ar, float& ai, float br, float bi) {
    float t = ar * br + ai * bi; ai = ai * br - ar * bi; ar = t;   // a *= conj(b)
}

__device__ __forceinline__ void dft4(float& x0r, float& x0i, float& x1r, float& x1i,
                                     float& x2r, float& x2i, float& x3r, float& x3i,
                                     float sg) {
    float t0r = x0r + x2r, t0i = x0i + x2i;
    float t1r = x0r - x2r, t1i = x0i - x2i;
    float t2r = x1r + x3r, t2i = x1i + x3i;
    float t3r = x1r - x3r, t3i = x1i - x3i;
    x0r = t0r + t2r; x0i = t0i + t2i;
    x2r = t0r - t2r; x2i = t0i - t2i;
    x1r = t1r - sg * t3i; x1i = t1i + sg * t3r;
    x3r = t1r + sg * t3i; x3i = t1i - sg * t3r;
}

template<int SG>
__device__ __forceinline__ void dft16_layer1(float* xr, float* xi) {
    const float sg = (float)SG;
#pragma unroll
    for (int n0 = 0; n0 < 4; ++n0)
        dft4(xr[n0], xi[n0], xr[n0 + 4], xi[n0 + 4],
             xr[n0 + 8], xi[n0 + 8], xr[n0 + 12], xi[n0 + 12], sg);
}
// upper 8 inputs (slots 8..15) known zero
template<int SG>
__device__ __forceinline__ void dft16_layer1_pad(float* xr, float* xi) {
    const float sg = (float)SG;
#pragma unroll
    for (int n0 = 0; n0 < 4; ++n0) {
        float ar = xr[n0], ai = xi[n0], br = xr[n0 + 4], bi = xi[n0 + 4];
        xr[n0]      = ar + br;       xi[n0]      = ai + bi;
        xr[n0 + 4]  = ar - sg * bi;  xi[n0 + 4]  = ai + sg * br;
        xr[n0 + 8]  = ar - br;       xi[n0 + 8]  = ai - bi;
        xr[n0 + 12] = ar + sg * bi;  xi[n0 + 12] = ai - sg * br;
    }
}
template<int SG>
__device__ __forceinline__ void dft16_twiddle(float* xr, float* xi) {
    const float sg = (float)SG;
    const float C1 = 0.923879532511286756f;
    const float S1 = 0.382683432365089772f;
    const float H  = 0.707106781186547524f;
    cmul(xr[5],  xi[5],  C1,  sg * S1);
    cmul(xr[9],  xi[9],  H,   sg * H);
    cmul(xr[13], xi[13], S1,  sg * C1);
    cmul(xr[6],  xi[6],  H,   sg * H);
    cmul(xr[10], xi[10], 0.f, sg);
    cmul(xr[14], xi[14], -H,  sg * H);
    cmul(xr[7],  xi[7],  S1,  sg * C1);
    cmul(xr[11], xi[11], -H,  sg * H);
    cmul(xr[15], xi[15], -C1, -sg * S1);
}
template<int SG>
__device__ __forceinline__ void dft16_layer2(float* xr, float* xi) {
    const float sg = (float)SG;
#pragma unroll
    for (int k1 = 0; k1 < 4; ++k1)
        dft4(xr[4 * k1], xi[4 * k1], xr[4 * k1 + 1], xi[4 * k1 + 1],
             xr[4 * k1 + 2], xi[4 * k1 + 2], xr[4 * k1 + 3], xi[4 * k1 + 3], sg);
}
template<int SG>
__device__ __forceinline__ void dft16(float* xr, float* xi) {
    dft16_layer1<SG>(xr, xi);
    dft16_twiddle<SG>(xr, xi);
    dft16_layer2<SG>(xr, xi);
}

// forward radix-16 stage with inline sincos twiddles (V build only, 1 block)
template<int L>
__device__ __forceinline__ void fwd_stage_sincos(float2* buf, int t) {
    constexpr int Lq = L / 16;
    int g = t / Lq;
    int j = t - g * Lq;
    int base = g * L + j;
    const float TPI = -6.28318530717958647692f;
    float xr[16], xi[16];
#pragma unroll
    for (int r = 0; r < 16; ++r) {
        float2 v = buf[P(base + r * Lq)];
        xr[r] = v.x; xi[r] = v.y;
    }
    dft16<-1>(xr, xi);
    { float2 v; v.x = xr[0]; v.y = xi[0]; buf[P(base)] = v; }
#pragma unroll
    for (int r = 1; r < 16; ++r) {
        float s, c;
        __sincosf(TPI * (float)(j * r) * (1.f / (float)L), &s, &c);
        float yr = xr[PERM(r)], yi = xi[PERM(r)];
        cmul(yr, yi, c, s);
        float2 v; v.x = yr; v.y = yi;
        buf[P(base + r * Lq)] = v;
    }
}

// ---------------- prep: tables + V + pair-interleaved transpose --------------
__global__ __launch_bounds__(256) void prep(const float* __restrict__ x,
                                            const float* __restrict__ pos,
                                            const float* __restrict__ zero,
                                            const float* __restrict__ neg,
                                            uint32_t* __restrict__ xP,
                                            float2* __restrict__ tw4096,
                                            float2* __restrict__ tw256,
                                            float2* __restrict__ V2) {
    __shared__ __align__(16) char smraw[32768];
    const float TPI = -6.28318530717958647692f;
    int blk = blockIdx.x, t = threadIdx.x;
    if (blk < 16) {
        float s, c;
        __sincosf(TPI * (float)(blk * t) * (1.f / 4096.f), &s, &c);
        float2 v; v.x = c; v.y = s;
        tw4096[blk * 256 + t] = v;
    } else if (blk == 16) {
        int r = t >> 4, j = t & 15;
        float s, c;
        __sincosf(TPI * (float)(r * j) * (1.f / 256.f), &s, &c);
        float2 v; v.x = c; v.y = s;
        tw256[t] = v;
    } else if (blk == 17) {
        float2* buf = (float2*)smraw;
#pragma unroll
        for (int it = 0; it < 16; ++it) {
            int n = t + 256 * it;
            float v;
            if (n == 0) v = zero[0];
            else if (n < N_) v = pos[n - 1];
            else if (n == N_) v = zero[0];
            else v = neg[n - (N_ + 1)];
            float2 cc; cc.x = v; cc.y = 0.f;
            buf[P(n)] = cc;
        }
        __syncthreads();
        fwd_stage_sincos<4096>(buf, t); __syncthreads();
        fwd_stage_sincos<256>(buf, t);  __syncthreads();
        fwd_stage_sincos<16>(buf, t);   __syncthreads();
        const float s = 1.f / (float)NF;
#pragma unroll
        for (int it = 0; it < 16; ++it) {
            int n = t + 256 * it;
            float2 c = buf[P(n)];
            c.x *= s; c.y *= s;
            V2[n] = c;
        }
    } else {
        float (*tile)[65] = (float (*)[65])smraw;    // 64*65*4 = 16.6 KB (pad 65: 2-way banks)
        int tid = blk - 18;
        int e0 = (tid & 15) * 64;                    // e-tile base
        int j0 = ((tid >> 4) & 31) * 64;             // n-tile base
        int b  = tid >> 9;
        int e4 = t & 15, jr = t >> 4;
#pragma unroll
        for (int it = 0; it < 4; ++it) {
            int j = jr + it * 16;
            const float4 v = *(const float4*)(x + ((size_t)(b * N_ + j0 + j) * E_) + e0 + e4 * 4);
            tile[e4 * 4 + 0][j] = v.x;
            tile[e4 * 4 + 1][j] = v.y;
            tile[e4 * 4 + 2][j] = v.z;
            tile[e4 * 4 + 3][j] = v.w;
        }
        __syncthreads();
        int jj = t & 63, ur = t >> 6;                // ur 0..3
#pragma unroll
        for (int it = 0; it < 8; ++it) {
            int u = ur + it * 4;                     // pair-local 0..31
            uint32_t w = cpack(tile[2 * u][jj], tile[2 * u + 1][jj]);
            xP[((size_t)(b * 512 + (e0 >> 1) + u)) * N_ + j0 + jj] = w;
        }
    }
}

// ---------------- main: FFT-conv, TWO pairs/block, bf16-packed LDS -----------
// v20 structure; only 2 barriers (after A, after D) -- B/C/D are wave-private.
__global__ __launch_bounds__(256) void fft_conv(const uint32_t* __restrict__ xP,
                                                const float2* __restrict__ tw4096,
                                                const float2* __restrict__ tw256,
                                                const float2* __restrict__ V2,
                                                float* __restrict__ out) {
    __shared__ uint32_t buf0[NF];           // 16 KB
    __shared__ uint32_t buf1[NF];           // 16 KB -> 32 KB total
    int t = threadIdx.x;
    int bid = blockIdx.x;                   // 2048
    int xcd = bid & 7;
    int q = bid >> 3;                       // 0..255
    int b = q >> 5;                         // 0..7
    int quad = xcd * 32 + (q & 31);         // 0..255 -> e0 = quad*4
    const uint32_t* g0 = xP + ((size_t)(b * 512 + quad * 2)) * N_;
    const uint32_t* g1 = g0 + N_;

    float x0r[16], x0i[16], x1r[16], x1i[16];

    // ---- Phase A: fwd L=4096 from global; slots 8..15 zero
#pragma unroll
    for (int r = 0; r < 8; ++r) {
        int n = t + 256 * r;
        cunpack(g0[n], x0r[r], x0i[r]);
        cunpack(g1[n], x1r[r], x1i[r]);
    }
#pragma unroll
    for (int r = 8; r < 16; ++r) { x0r[r] = 0.f; x0i[r] = 0.f; x1r[r] = 0.f; x1i[r] = 0.f; }
    dft16_layer1_pad<-1>(x0r, x0i); dft16_layer1_pad<-1>(x1r, x1i);
    dft16_twiddle<-1>(x0r, x0i);    dft16_twiddle<-1>(x1r, x1i);
    dft16_layer2<-1>(x0r, x0i);     dft16_layer2<-1>(x1r, x1i);
    {
        const int bAE = (t ^ (t >> 4)) << 2;
        ldsw(buf0, bAE, cpack(x0r[0], x0i[0]));
        ldsw(buf1, bAE, cpack(x1r[0], x1i[0]));
#pragma unroll
        for (int r = 1; r < 16; ++r) {
            float2 w = tw4096[r * 256 + t];             // shared twiddle
            int a = bAE ^ KAE(r);
            float y0r = x0r[PERM(r)], y0i = x0i[PERM(r)];
            cmul(y0r, y0i, w.x, w.y);
            ldsw(buf0, a, cpack(y0r, y0i));
            float y1r = x1r[PERM(r)], y1i = x1i[PERM(r)];
            cmul(y1r, y1i, w.x, w.y);
            ldsw(buf1, a, cpack(y1r, y1i));
        }
    }
    __syncthreads();                        // A wrote ALL groups: cross-wave

    // ---- Phase B: fwd L=256 (group t>>4 only -- wave-private from here)
    {
        const int gg = t >> 4, j = t & 15;
        const int bBD = ((gg << 8) ^ j ^ gg ^ (((gg >> 1) & 1) << 4)) << 2;
#pragma unroll
        for (int r = 0; r < 16; ++r) {
            int a = bBD ^ KBD(r);
            cunpack(ldsr(buf0, a), x0r[r], x0i[r]);
            cunpack(ldsr(buf1, a), x1r[r], x1i[r]);
        }
        dft16<-1>(x0r, x0i); dft16<-1>(x1r, x1i);
        ldsw(buf0, bBD, cpack(x0r[0], x0i[0]));
        ldsw(buf1, bBD, cpack(x1r[0], x1i[0]));
#pragma unroll
        for (int r = 1; r < 16; ++r) {
            float2 w = tw256[r * 16 + j];
            int a = bBD ^ KBD(r);
            float y0r = x0r[PERM(r)], y0i = x0i[PERM(r)];
            cmul(y0r, y0i, w.x, w.y);
            ldsw(buf0, a, cpack(y0r, y0i));
            float y1r = x1r[PERM(r)], y1i = x1i[PERM(r)];
            cmul(y1r, y1i, w.x, w.y);
            ldsw(buf1, a, cpack(y1r, y1i));
        }
    }
    // no barrier: B->C exchange is within group t>>4 (wave-private)

    // ---- Phase C: fwd L=16 + pointwise*V (shared) + inv L=16, in place
    {
        const int bC = ((t << 4) ^ (t & 15) ^ ((t >> 4) & 15) ^ (((t >> 5) & 1) << 4)) << 2;
        int mb = 16 * t;
#pragma unroll
        for (int r = 0; r < 16; ++r) {
            int a = bC ^ (r << 2);
            cunpack(ldsr(buf0, a), x0r[r], x0i[r]);
            cunpack(ldsr(buf1, a), x1r[r], x1i[r]);
        }
        dft16<-1>(x0r, x0i); dft16<-1>(x1r, x1i);
        // y[r] = x[PERM(r)]*V[r]; PERM involution -> pair swap, V shared
#pragma unroll
        for (int r = 0; r < 16; ++r) {
            int p = PERM(r);
            if (p < r) continue;
            if (p == r) {
                float2 vv = V2[mb + r];
                float ar = x0r[r], ai = x0i[r];
                x0r[r] = ar * vv.x - ai * vv.y; x0i[r] = ar * vv.y + ai * vv.x;
                ar = x1r[r]; ai = x1i[r];
                x1r[r] = ar * vv.x - ai * vv.y; x1i[r] = ar * vv.y + ai * vv.x;
            } else {
                float2 va = V2[mb + r], vb = V2[mb + p];
                float ar = x0r[r], ai = x0i[r], br = x0r[p], bi = x0i[p];
                x0r[r] = br * va.x - bi * va.y; x0i[r] = br * va.y + bi * va.x;
                x0r[p] = ar * vb.x - ai * vb.y; x0i[p] = ar * vb.y + ai * vb.x;
                ar = x1r[r]; ai = x1i[r]; br = x1r[p]; bi = x1i[p];
                x1r[r] = br * va.x - bi * va.y; x1i[r] = br * va.y + bi * va.x;
                x1r[p] = ar * vb.x - ai * vb.y; x1i[p] = ar * vb.y + ai * vb.x;
            }
        }
        dft16<1>(x0r, x0i); dft16<1>(x1r, x1i);
#pragma unroll
        for (int r = 0; r < 16; ++r) {
            int a = bC ^ (r << 2);
            ldsw(buf0, a, cpack(x0r[PERM(r)], x0i[PERM(r)]));
            ldsw(buf1, a, cpack(x1r[PERM(r)], x1i[PERM(r)]));
        }
    }
    // no barrier: C->D exchange is within group t>>4 (wave-private)

    // ---- Phase D: inv L=256
    {
        const int gg = t >> 4, j = t & 15;
        const int bBD = ((gg << 8) ^ j ^ gg ^ (((gg >> 1) & 1) << 4)) << 2;
#pragma unroll
        for (int r = 0; r < 16; ++r) {
            int a = bBD ^ KBD(r);
            cunpack(ldsr(buf0, a), x0r[r], x0i[r]);
            cunpack(ldsr(buf1, a), x1r[r], x1i[r]);
        }
#pragma unroll
        for (int r = 1; r < 16; ++r) {
            float2 w = tw256[r * 16 + j];
            cmulc(x0r[r], x0i[r], w.x, w.y);
            cmulc(x1r[r], x1i[r], w.x, w.y);
        }
        dft16<1>(x0r, x0i); dft16<1>(x1r, x1i);
#pragma unroll
        for (int r = 0; r < 16; ++r) {
            int a = bBD ^ KBD(r);
            ldsw(buf0, a, cpack(x0r[PERM(r)], x0i[PERM(r)]));
            ldsw(buf1, a, cpack(x1r[PERM(r)], x1i[PERM(r)]));
        }
    }
    __syncthreads();                        // E reads ALL groups: cross-wave

    // ---- Phase E: inv L=4096, pruned (k<2048), fused float4 stores (4 cols)
    {
        const int bAE = (t ^ (t >> 4)) << 2;
#pragma unroll
        for (int r = 0; r < 16; ++r) {
            int a = bAE ^ KAE(r);
            cunpack(ldsr(buf0, a), x0r[r], x0i[r]);
            cunpack(ldsr(buf1, a), x1r[r], x1i[r]);
        }
    }
#pragma unroll
    for (int r = 1; r < 16; ++r) {
        float2 w = tw4096[r * 256 + t];
        cmulc(x0r[r], x0i[r], w.x, w.y);
        cmulc(x1r[r], x1i[r], w.x, w.y);
    }
    dft16_layer1<1>(x0r, x0i); dft16_layer1<1>(x1r, x1i);
    dft16_twiddle<1>(x0r, x0i); dft16_twiddle<1>(x1r, x1i);
    float* ob = out + ((size_t)b * N_) * E_ + quad * 4;
#pragma unroll
    for (int k1 = 0; k1 < 4; ++k1) {
        // pruned final dft4 (outputs r=k1 and r=k1+4 only), both streams
        float a0r = x0r[4 * k1],     a0i = x0i[4 * k1];
        float a1r = x0r[4 * k1 + 1], a1i = x0i[4 * k1 + 1];
        float a2r = x0r[4 * k1 + 2], a2i = x0i[4 * k1 + 2];
        float a3r = x0r[4 * k1 + 3], a3i = x0i[4 * k1 + 3];
        float t0r = a0r + a2r, t0i = a0i + a2i;
        float t1r = a0r - a2r, t1i = a0i - a2i;
        float t2r = a1r + a3r, t2i = a1i + a3i;
        float t3r = a1r - a3r, t3i = a1i - a3i;
        float s0v0r = t0r + t2r, s0v0i = t0i + t2i;
        float s0v1r = t1r - t3i, s0v1i = t1i + t3r;
        a0r = x1r[4 * k1];     a0i = x1i[4 * k1];
        a1r = x1r[4 * k1 + 1]; a1i = x1i[4 * k1 + 1];
        a2r = x1r[4 * k1 + 2]; a2i = x1i[4 * k1 + 2];
        a3r = x1r[4 * k1 + 3]; a3i = x1i[4 * k1 + 3];
        t0r = a0r + a2r; t0i = a0i + a2i;
        t1r = a0r - a2r; t1i = a0i - a2i;
        t2r = a1r + a3r; t2i = a1i + a3i;
        t3r = a1r - a3r; t3i = a1i - a3i;
        float s1v0r = t0r + t2r, s1v0i = t0i + t2i;
        float s1v1r = t1r - t3i, s1v1i = t1i + t3r;
        float4 w0; w0.x = s0v0r; w0.y = s0v0i; w0.z = s1v0r; w0.w = s1v0i;
        float4 w1; w1.x = s0v1r; w1.y = s0v1i; w1.z = s1v1r; w1.w = s1v1i;
        *(float4*)(ob + (size_t)(t + 256 * k1) * E_)       = w0;   // k=t+256k1
        *(float4*)(ob + (size_t)(t + 256 * (k1 + 4)) * E_) = w1;   // k=t+256(k1+4)
    }
}

// ---------------- fallback (ws too small): direct fp32 dot -------------------
__global__ __launch_bounds__(256) void naive_toep(const float* __restrict__ x,
                                                  const float* __restrict__ pos,
                                                  const float* __restrict__ zero,
                                                  const float* __restrict__ neg,
                                                  float* __restrict__ out) {
    int bid = blockIdx.x;
    int e   = (bid & 3) * 256 + threadIdx.x;
    int k   = (bid >> 2) & (N_ - 1);
    int b   = bid >> 13;
    float zv = zero[0];
    float acc = 0.f;
    const float* xb = x + (size_t)b * N_ * E_ + e;
    for (int jj = 0; jj < N_; ++jj) {
        float c = (jj < k) ? pos[k - jj - 1] : (jj == k) ? zv : neg[N_ - 1 - jj + k];
        acc += c * xb[(size_t)jj * E_];
    }
    out[((size_t)(b * N_ + k)) * E_ + e] = acc;
}

extern "C" void kernel_launch(void* const* d_in, const int* in_sizes, int n_in,
                              void* d_out, int out_size, void* d_ws, size_t ws_size,
                              hipStream_t stream) {
    const float* x    = (const float*)d_in[0];
    const float* pos  = (const float*)d_in[1];
    const float* zero = (const float*)d_in[2];
    const float* neg  = (const float*)d_in[3];
    float* out = (float*)d_out;

    const size_t needX = (size_t)B_ * 512 * N_ * sizeof(uint32_t);   // 32 MiB
    const size_t need  = needX + (2 * (size_t)NF + 256) * sizeof(float2);
    if (ws_size >= need) {
        uint32_t* xP   = (uint32_t*)d_ws;
        float2* tw4096 = (float2*)((char*)d_ws + needX);
        float2* tw256  = tw4096 + NF;
        float2* V2     = tw256 + 256;
        prep<<<18 + 4096, 256, 0, stream>>>(x, pos, zero, neg, xP, tw4096, tw256, V2);
        fft_conv<<<2048, 256, 0, stream>>>(xP, tw4096, tw256, V2, out);
    } else {
        naive_toep<<<65536, 256, 0, stream>>>(x, pos, zero, neg, out);
    }
}